// Round 6
// baseline (368.188 us; speedup 1.0000x reference)
//
#include <hip/hip_runtime.h>
#include <hip/hip_bf16.h>

#define V_NODES 100000
#define DIM 128
#define BATCH 16384
#define SAMP 64
#define NEDGE 640000
#define NSAMP (BATCH * SAMP)

// bf16 helpers: raw-bit unpack (exact) and RNE pack
__device__ __forceinline__ float bl(unsigned u) { return __uint_as_float(u << 16); }
__device__ __forceinline__ float bh(unsigned u) { return __uint_as_float(u & 0xffff0000u); }
__device__ __forceinline__ unsigned short f2bf(float x) {
    unsigned u = __float_as_uint(x);
    return (unsigned short)((u + 0x7fffu + ((u >> 16) & 1u)) >> 16);
}

// ---------- K0: fp32 -> bf16 table conversion (emb_h) ----------
__global__ void k_cvt(const float* __restrict__ in, unsigned short* __restrict__ outh, int n4) {
    int i = blockIdx.x * blockDim.x + threadIdx.x;
    if (i < n4) {
        float4 v = ((const float4*)in)[i];
        ushort4 o;
        o.x = f2bf(v.x); o.y = f2bf(v.y); o.z = f2bf(v.z); o.w = f2bf(v.w);
        ((ushort4*)outh)[i] = o;
    }
}

// ---------- K1: histogram by key (used for edge-dst AND sample-id counting sorts) ----------
__global__ void k_count(const int* __restrict__ key, int* __restrict__ cnt, int E) {
    int e = blockIdx.x * blockDim.x + threadIdx.x;
    if (e < E) atomicAdd(&cnt[key[e]], 1);
}

// ---------- K2a: per-1024-chunk sums ----------
__global__ void k_bsum(const int* __restrict__ cnt, int* __restrict__ bsum, int V) {
    __shared__ int red[4];
    int b = blockIdx.x, t = threadIdx.x;
    int s = 0;
    int base = b * 1024;
    for (int i = 0; i < 4; ++i) {
        int idx = base + i * 256 + t;
        if (idx < V) s += cnt[idx];
    }
    for (int m = 32; m >= 1; m >>= 1) s += __shfl_xor(s, m, 64);
    int lane = t & 63, wid = t >> 6;
    if (lane == 0) red[wid] = s;
    __syncthreads();
    if (t == 0) bsum[b] = red[0] + red[1] + red[2] + red[3];
}

// ---------- K2b: tiny serial scan of chunk sums ----------
__global__ void k_bscan(const int* __restrict__ bsum, int* __restrict__ boff, int nb) {
    if (threadIdx.x == 0 && blockIdx.x == 0) {
        int run = 0;
        for (int i = 0; i < nb; ++i) { boff[i] = run; run += bsum[i]; }
    }
}

// ---------- K2c: exclusive offsets + dinv = 1/sqrt(deg+1)  (edge CSR) ----------
__global__ void k_offs(const int* __restrict__ cnt, const int* __restrict__ boff,
                       int* __restrict__ offs, float* __restrict__ dinv, int V) {
    __shared__ int wsum[4];
    int b = blockIdx.x, t = threadIdx.x;
    int lane = t & 63, wid = t >> 6;
    int base = b * 1024 + t * 4;
    int c[4];
    for (int j = 0; j < 4; ++j) {
        int idx = base + j;
        c[j] = (idx < V) ? cnt[idx] : 0;
    }
    int tot = c[0] + c[1] + c[2] + c[3];
    int x = tot;
    for (int off = 1; off < 64; off <<= 1) {
        int n = __shfl_up(x, off, 64);
        if (lane >= off) x += n;
    }
    int lex = x - tot;
    if (lane == 63) wsum[wid] = x;
    __syncthreads();
    int wpre = 0;
    for (int w = 0; w < wid; ++w) wpre += wsum[w];
    int o = boff[b] + wpre + lex;
    int pre = 0;
    for (int j = 0; j < 4; ++j) {
        int idx = base + j;
        if (idx < V) {
            offs[idx] = o + pre;
            dinv[idx] = 1.0f / sqrtf((float)(c[j] + 1));
        }
        pre += c[j];
    }
}

// ---------- K2c': exclusive offsets only (sample sort) ----------
__global__ void k_offs2(const int* __restrict__ cnt, const int* __restrict__ boff,
                        int* __restrict__ offs, int V) {
    __shared__ int wsum[4];
    int b = blockIdx.x, t = threadIdx.x;
    int lane = t & 63, wid = t >> 6;
    int base = b * 1024 + t * 4;
    int c[4];
    for (int j = 0; j < 4; ++j) {
        int idx = base + j;
        c[j] = (idx < V) ? cnt[idx] : 0;
    }
    int tot = c[0] + c[1] + c[2] + c[3];
    int x = tot;
    for (int off = 1; off < 64; off <<= 1) {
        int n = __shfl_up(x, off, 64);
        if (lane >= off) x += n;
    }
    int lex = x - tot;
    if (lane == 63) wsum[wid] = x;
    __syncthreads();
    int wpre = 0;
    for (int w = 0; w < wid; ++w) wpre += wsum[w];
    int o = boff[b] + wpre + lex;
    int pre = 0;
    for (int j = 0; j < 4; ++j) {
        int idx = base + j;
        if (idx < V) offs[idx] = o + pre;
        pre += c[j];
    }
}

// ---------- K3: fill edge CSR (int atomic cursors) ----------
__global__ void k_fill(const int* __restrict__ src, const int* __restrict__ dst,
                       const int* __restrict__ offs, int* __restrict__ cursor,
                       int* __restrict__ csr, int E) {
    int e = blockIdx.x * blockDim.x + threadIdx.x;
    if (e < E) {
        int d = dst[e];
        int pos = atomicAdd(&cursor[d], 1);
        csr[offs[d] + pos] = src[e];
    }
}

// ---------- K3': fill sorted (id, dest) pairs for scoring ----------
__global__ void k_sfill(const int* __restrict__ samples, const int* __restrict__ offs,
                        int* __restrict__ cursor, uint2* __restrict__ pairs, int n) {
    int i = blockIdx.x * blockDim.x + threadIdx.x;
    if (i < n) {
        int id = samples[i];
        int pos = atomicAdd(&cursor[id], 1);
        pairs[offs[id] + pos] = make_uint2((unsigned)id, (unsigned)i);
    }
}

// ---------- K4: aggregate in EMBEDDING space, bf16 gathers ----------
__global__ __launch_bounds__(256) void k_agg(const unsigned short* __restrict__ emb_h,
                     const int* __restrict__ offs, const int* __restrict__ cnt,
                     const int* __restrict__ csr, const float* __restrict__ dinv,
                     float* __restrict__ out, int V) {
    int wid = threadIdx.x >> 6;
    int lane = threadIdx.x & 63;
    int v = blockIdx.x * 4 + wid;
    if (v >= V) return;
    float dv = dinv[v];
    int beg = offs[v], num = cnt[v];
    int nid = 0; float nw = 0.0f;
    if (lane < num) {
        nid = csr[beg + lane];
        nw = dinv[nid];
    }
    unsigned u0 = ((const unsigned*)(emb_h + (size_t)v * DIM))[lane];
    float wself = dv * dv;
    float2 acc;
    acc.x = wself * bl(u0); acc.y = wself * bh(u0);
    int n0 = min(num, 64);
    for (int i = 0; i < n0; ++i) {
        int s = __shfl(nid, i, 64);
        float w = dv * __shfl(nw, i, 64);
        unsigned u = ((const unsigned*)(emb_h + (size_t)s * DIM))[lane];
        acc.x += w * bl(u); acc.y += w * bh(u);
    }
    for (int i = 64; i < num; ++i) {
        int s = csr[beg + i];
        float w = dv * dinv[s];
        unsigned u = ((const unsigned*)(emb_h + (size_t)s * DIM))[lane];
        acc.x += w * bl(u); acc.y += w * bh(u);
    }
    ((float2*)(out + (size_t)v * DIM))[lane] = acc;
}

// ---------- K5: GEMM  nodes_h = bf16(nodes @ W + bias)  (fp32 copy is dead -> not written) ----------
__global__ __launch_bounds__(256) void k_gemm(const float* __restrict__ nodes,
                      unsigned short* __restrict__ nodes_h,
                      const float* __restrict__ W, const float* __restrict__ bias, int V) {
    __shared__ float rows[32][128];
    __shared__ float wld[32][128];
    int t = threadIdx.x;
    int rowbase = blockIdx.x * 32;
    {
        const float4* g = (const float4*)(nodes + (size_t)rowbase * DIM);
        float4* s = (float4*)&rows[0][0];
        #pragma unroll
        for (int i = 0; i < 4; ++i) s[t + i * 256] = g[t + i * 256];
    }
    int tr = t >> 5, tc = t & 31;
    float acc[4][4] = {{0.f}};
    for (int kt = 0; kt < 4; ++kt) {
        __syncthreads();
        {
            const float4* g = (const float4*)(W + kt * 32 * DIM);
            float4* s = (float4*)&wld[0][0];
            #pragma unroll
            for (int i = 0; i < 4; ++i) s[t + i * 256] = g[t + i * 256];
        }
        __syncthreads();
        #pragma unroll
        for (int k = 0; k < 32; ++k) {
            float4 wv = *(const float4*)&wld[k][tc * 4];
            float a0 = rows[tr * 4 + 0][kt * 32 + k];
            float a1 = rows[tr * 4 + 1][kt * 32 + k];
            float a2 = rows[tr * 4 + 2][kt * 32 + k];
            float a3 = rows[tr * 4 + 3][kt * 32 + k];
            acc[0][0] += a0 * wv.x; acc[0][1] += a0 * wv.y; acc[0][2] += a0 * wv.z; acc[0][3] += a0 * wv.w;
            acc[1][0] += a1 * wv.x; acc[1][1] += a1 * wv.y; acc[1][2] += a1 * wv.z; acc[1][3] += a1 * wv.w;
            acc[2][0] += a2 * wv.x; acc[2][1] += a2 * wv.y; acc[2][2] += a2 * wv.z; acc[2][3] += a2 * wv.w;
            acc[3][0] += a3 * wv.x; acc[3][1] += a3 * wv.y; acc[3][2] += a3 * wv.z; acc[3][3] += a3 * wv.w;
        }
    }
    float4 bv = *(const float4*)&bias[tc * 4];
    #pragma unroll
    for (int i = 0; i < 4; ++i) {
        int r = rowbase + tr * 4 + i;
        if (r < V) {
            ushort4 oh;
            oh.x = f2bf(acc[i][0] + bv.x); oh.y = f2bf(acc[i][1] + bv.y);
            oh.z = f2bf(acc[i][2] + bv.z); oh.w = f2bf(acc[i][3] + bv.w);
            *(ushort4*)(nodes_h + (size_t)r * DIM + tc * 4) = oh;
        }
    }
}

// ---------- K6a: compact item rows -> items_bf [B,128] bf16 (4 MB) ----------
__global__ __launch_bounds__(256) void k_items(const unsigned short* __restrict__ nodes_h,
        const int* __restrict__ items, unsigned short* __restrict__ items_bf) {
    int w = (blockIdx.x * blockDim.x + threadIdx.x) >> 6;
    int lane = threadIdx.x & 63;
    if (w >= BATCH) return;
    int id = items[w];
    unsigned v = ((const unsigned*)(nodes_h + (size_t)id * DIM))[lane];
    ((unsigned*)(items_bf + (size_t)w * DIM))[lane] = v;
}

// ---------- K6b: scoring over id-sorted pairs: node-row reads are STREAMING ----------
// 4 threads per pair (each owns 32 dims); consecutive groups hit consecutive /
// repeated node rows (avg ~10 repeats per row -> L1 hits + one 25.6 MB stream).
__global__ __launch_bounds__(256) void k_score3(const unsigned short* __restrict__ nodes_h,
        const unsigned short* __restrict__ items_bf, const uint2* __restrict__ pairs,
        float* __restrict__ out) {
    int g = (blockIdx.x * blockDim.x + threadIdx.x) >> 2;   // pair index
    int q = threadIdx.x & 3;                                // dim-chunk 0..3
    if (g >= NSAMP) return;
    uint2 pr = pairs[g];
    int id = (int)pr.x, dest = (int)pr.y;
    const uint4* nrow = (const uint4*)(nodes_h + (size_t)id * DIM) + q * 4;
    const uint4* irow = (const uint4*)(items_bf + (size_t)(dest >> 6) * DIM) + q * 4;
    uint4 a[4], b[4];
    #pragma unroll
    for (int c = 0; c < 4; ++c) a[c] = nrow[c];
    #pragma unroll
    for (int c = 0; c < 4; ++c) b[c] = irow[c];
    float p = 0.f;
    #pragma unroll
    for (int c = 0; c < 4; ++c) {
        uint4 av = a[c], bv = b[c];
        p += bl(av.x) * bl(bv.x) + bh(av.x) * bh(bv.x);
        p += bl(av.y) * bl(bv.y) + bh(av.y) * bh(bv.y);
        p += bl(av.z) * bl(bv.z) + bh(av.z) * bh(bv.z);
        p += bl(av.w) * bl(bv.w) + bh(av.w) * bh(bv.w);
    }
    p += __shfl_xor(p, 1, 64);
    p += __shfl_xor(p, 2, 64);
    if (q == 0) out[dest] = p;
}

extern "C" void kernel_launch(void* const* d_in, const int* in_sizes, int n_in,
                              void* d_out, int out_size, void* d_ws, size_t ws_size,
                              hipStream_t stream) {
    const int*   items   = (const int*)d_in[0];
    const int*   samples = (const int*)d_in[1];
    const int*   edges   = (const int*)d_in[2];
    const float* emb     = (const float*)d_in[3];
    const float* W       = (const float*)d_in[4];
    const float* bias    = (const float*)d_in[5];
    float* out = (float*)d_out;

    char* ws = (char*)d_ws;
    // --- static region (never aliased) ---
    int*   cnt    = (int*)(ws + 0);                        // V ints (400 KB)
    int*   cursor = (int*)(ws + (512 << 10));              // V ints
    float* dinv   = (float*)(ws + (1 << 20));              // V floats
    int*   offs   = (int*)(ws + 3 * (512 << 10));          // V ints
    int*   bsum   = (int*)(ws + (2 << 20));                // 98 ints
    int*   boff   = (int*)(ws + (2 << 20) + (4 << 10));    // 98 ints
    int*   bsum2  = (int*)(ws + (2 << 20) + (8 << 10));    // 98 ints
    int*   boff2  = (int*)(ws + (2 << 20) + (12 << 10));   // 98 ints
    int*   cnt2   = (int*)(ws + (2 << 20) + (64 << 10));   // V ints   (2M+64K .. 2M+464K)
    int*   cur2   = (int*)(ws + (2 << 20) + (512 << 10));  // V ints   (2M+512K .. 2M+912K)
    int*   offs2  = (int*)(ws + (2 << 20) + (960 << 10));  // V ints   (2M+960K .. 2M+1360K)
    int*   csr    = (int*)(ws + (4 << 20));                // E ints (2.56 MB)
    unsigned short* emb_h   = (unsigned short*)(ws + (8 << 20));   // V*DIM bf16 (25.6 MB)
    unsigned short* nodes_h = emb_h;                       // alias: emb_h dead after k_agg
    float* nodes  = (float*)(ws + (34 << 20));             // V*DIM fp32 (34..85.2 MB), dead after k_gemm
    // --- overlays on dead fp32 nodes (only written after k_gemm) ---
    uint2* pairs = (uint2*)(ws + (34 << 20));                      // 1M uint2 (8 MB)
    unsigned short* items_bf = (unsigned short*)(ws + (44 << 20)); // B*DIM bf16 (4 MB)

    const int* esrc = edges;
    const int* edst = edges + NEDGE;

    hipMemsetAsync(ws, 0, (1 << 20), stream);                          // cnt + cursor
    hipMemsetAsync(ws + (2 << 20) + (64 << 10), 0, 848 << 10, stream); // cnt2 .. cur2

    int nb = (V_NODES + 1023) / 1024;   // 98
    int n4 = V_NODES * DIM / 4;
    k_cvt  <<<(n4 + 255) / 256, 256, 0, stream>>>(emb, emb_h, n4);
    // edge CSR (by dst)
    k_count<<<(NEDGE + 255) / 256, 256, 0, stream>>>(edst, cnt, NEDGE);
    k_bsum <<<nb, 256, 0, stream>>>(cnt, bsum, V_NODES);
    k_bscan<<<1, 64, 0, stream>>>(bsum, boff, nb);
    k_offs <<<nb, 256, 0, stream>>>(cnt, boff, offs, dinv, V_NODES);
    k_fill <<<(NEDGE + 255) / 256, 256, 0, stream>>>(esrc, edst, offs, cursor, csr, NEDGE);
    // sample counting-sort offsets (metadata only; pairs filled after k_gemm)
    k_count<<<(NSAMP + 255) / 256, 256, 0, stream>>>(samples, cnt2, NSAMP);
    k_bsum <<<nb, 256, 0, stream>>>(cnt2, bsum2, V_NODES);
    k_bscan<<<1, 64, 0, stream>>>(bsum2, boff2, nb);
    k_offs2<<<nb, 256, 0, stream>>>(cnt2, boff2, offs2, V_NODES);
    // GCN
    k_agg  <<<(V_NODES + 3) / 4, 256, 0, stream>>>(emb_h, offs, cnt, csr, dinv, nodes, V_NODES);
    k_gemm <<<V_NODES / 32, 256, 0, stream>>>(nodes, nodes_h, W, bias, V_NODES);
    // scoring (nodes fp32 dead; overlays live from here)
    k_items<<<BATCH / 4, 256, 0, stream>>>(nodes_h, items, items_bf);
    k_sfill<<<(NSAMP + 255) / 256, 256, 0, stream>>>(samples, offs2, cur2, pairs, NSAMP);
    k_score3<<<(NSAMP * 4 + 255) / 256, 256, 0, stream>>>(nodes_h, items_bf, pairs, out);
}

// Round 7
// 224.555 us; speedup vs baseline: 1.6396x; 1.6396x over previous
//
#include <hip/hip_runtime.h>
#include <hip/hip_bf16.h>

#define V_NODES 100000
#define DIM 128
#define BATCH 16384
#define SAMP 64
#define NEDGE 640000
#define NSAMP (BATCH * SAMP)

// bf16 helpers: raw-bit unpack (exact) and RNE pack
__device__ __forceinline__ float bl(unsigned u) { return __uint_as_float(u << 16); }
__device__ __forceinline__ float bh(unsigned u) { return __uint_as_float(u & 0xffff0000u); }
__device__ __forceinline__ unsigned short f2bf(float x) {
    unsigned u = __float_as_uint(x);
    return (unsigned short)((u + 0x7fffu + ((u >> 16) & 1u)) >> 16);
}

// ---------- K1: histogram of edge destinations (in-degree) ----------
__global__ void k_count(const int* __restrict__ key, int* __restrict__ cnt, int E) {
    int e = blockIdx.x * blockDim.x + threadIdx.x;
    if (e < E) atomicAdd(&cnt[key[e]], 1);
}

// ---------- K2a: per-1024-chunk sums ----------
__global__ void k_bsum(const int* __restrict__ cnt, int* __restrict__ bsum, int V) {
    __shared__ int red[4];
    int b = blockIdx.x, t = threadIdx.x;
    int s = 0;
    int base = b * 1024;
    for (int i = 0; i < 4; ++i) {
        int idx = base + i * 256 + t;
        if (idx < V) s += cnt[idx];
    }
    for (int m = 32; m >= 1; m >>= 1) s += __shfl_xor(s, m, 64);
    int lane = t & 63, wid = t >> 6;
    if (lane == 0) red[wid] = s;
    __syncthreads();
    if (t == 0) bsum[b] = red[0] + red[1] + red[2] + red[3];
}

// ---------- K2b: tiny serial scan of chunk sums ----------
__global__ void k_bscan(const int* __restrict__ bsum, int* __restrict__ boff, int nb) {
    if (threadIdx.x == 0 && blockIdx.x == 0) {
        int run = 0;
        for (int i = 0; i < nb; ++i) { boff[i] = run; run += bsum[i]; }
    }
}

// ---------- K2c: exclusive CSR offsets + dinv = 1/sqrt(deg+1) ----------
__global__ void k_offs(const int* __restrict__ cnt, const int* __restrict__ boff,
                       int* __restrict__ offs, float* __restrict__ dinv, int V) {
    __shared__ int wsum[4];
    int b = blockIdx.x, t = threadIdx.x;
    int lane = t & 63, wid = t >> 6;
    int base = b * 1024 + t * 4;
    int c[4];
    for (int j = 0; j < 4; ++j) {
        int idx = base + j;
        c[j] = (idx < V) ? cnt[idx] : 0;
    }
    int tot = c[0] + c[1] + c[2] + c[3];
    int x = tot;
    for (int off = 1; off < 64; off <<= 1) {
        int n = __shfl_up(x, off, 64);
        if (lane >= off) x += n;
    }
    int lex = x - tot;
    if (lane == 63) wsum[wid] = x;
    __syncthreads();
    int wpre = 0;
    for (int w = 0; w < wid; ++w) wpre += wsum[w];
    int o = boff[b] + wpre + lex;
    int pre = 0;
    for (int j = 0; j < 4; ++j) {
        int idx = base + j;
        if (idx < V) {
            offs[idx] = o + pre;
            dinv[idx] = 1.0f / sqrtf((float)(c[j] + 1));
        }
        pre += c[j];
    }
}

// ---------- K3: fill edge CSR (int atomic cursors) ----------
__global__ void k_fill(const int* __restrict__ src, const int* __restrict__ dst,
                       const int* __restrict__ offs, int* __restrict__ cursor,
                       int* __restrict__ csr, int E) {
    int e = blockIdx.x * blockDim.x + threadIdx.x;
    if (e < E) {
        int d = dst[e];
        int pos = atomicAdd(&cursor[d], 1);
        csr[offs[d] + pos] = src[e];
    }
}

// ---------- K4: GEMM first (reference order):  h_bf = bf16(emb @ W) ----------
// 256 thr = 8 row-groups x 32 col-groups; each thread 4x4 register tile.
__global__ __launch_bounds__(256) void k_hgemm(const float* __restrict__ emb,
                      unsigned short* __restrict__ h_bf,
                      const float* __restrict__ W, int V) {
    __shared__ float rows[32][128];   // 16 KB
    __shared__ float wld[32][128];    // 16 KB
    int t = threadIdx.x;
    int rowbase = blockIdx.x * 32;
    {   // stage 32 emb rows (4096 floats) as float4
        const float4* g = (const float4*)(emb + (size_t)rowbase * DIM);
        float4* s = (float4*)&rows[0][0];
        #pragma unroll
        for (int i = 0; i < 4; ++i) s[t + i * 256] = g[t + i * 256];
    }
    int tr = t >> 5, tc = t & 31;
    float acc[4][4] = {{0.f}};
    for (int kt = 0; kt < 4; ++kt) {
        __syncthreads();
        {   // stage W rows [kt*32, kt*32+32)
            const float4* g = (const float4*)(W + kt * 32 * DIM);
            float4* s = (float4*)&wld[0][0];
            #pragma unroll
            for (int i = 0; i < 4; ++i) s[t + i * 256] = g[t + i * 256];
        }
        __syncthreads();
        #pragma unroll
        for (int k = 0; k < 32; ++k) {
            float4 wv = *(const float4*)&wld[k][tc * 4];
            float a0 = rows[tr * 4 + 0][kt * 32 + k];
            float a1 = rows[tr * 4 + 1][kt * 32 + k];
            float a2 = rows[tr * 4 + 2][kt * 32 + k];
            float a3 = rows[tr * 4 + 3][kt * 32 + k];
            acc[0][0] += a0 * wv.x; acc[0][1] += a0 * wv.y; acc[0][2] += a0 * wv.z; acc[0][3] += a0 * wv.w;
            acc[1][0] += a1 * wv.x; acc[1][1] += a1 * wv.y; acc[1][2] += a1 * wv.z; acc[1][3] += a1 * wv.w;
            acc[2][0] += a2 * wv.x; acc[2][1] += a2 * wv.y; acc[2][2] += a2 * wv.z; acc[2][3] += a2 * wv.w;
            acc[3][0] += a3 * wv.x; acc[3][1] += a3 * wv.y; acc[3][2] += a3 * wv.z; acc[3][3] += a3 * wv.w;
        }
    }
    #pragma unroll
    for (int i = 0; i < 4; ++i) {
        int r = rowbase + tr * 4 + i;
        if (r < V) {
            ushort4 oh;
            oh.x = f2bf(acc[i][0]); oh.y = f2bf(acc[i][1]);
            oh.z = f2bf(acc[i][2]); oh.w = f2bf(acc[i][3]);
            *(ushort4*)(h_bf + (size_t)r * DIM + tc * 4) = oh;
        }
    }
}

// ---------- K5: aggregate h (post-GEMM), + bias, write bf16 nodes ----------
// one wave per node; lane holds 2 dims (one packed bf16x2 = 4B).
// Neighbor ids + dinv prefetched lane-parallel, broadcast via shuffle.
__global__ __launch_bounds__(256) void k_agg(const unsigned short* __restrict__ h_bf,
                     const int* __restrict__ offs, const int* __restrict__ cnt,
                     const int* __restrict__ csr, const float* __restrict__ dinv,
                     const float* __restrict__ bias,
                     unsigned* __restrict__ nodes_h, int V) {
    int wid = threadIdx.x >> 6;
    int lane = threadIdx.x & 63;
    int v = blockIdx.x * 4 + wid;
    if (v >= V) return;
    float dv = dinv[v];
    int beg = offs[v], num = cnt[v];
    int nid = 0; float nw = 0.0f;
    if (lane < num) {                       // one coalesced id load + one dinv gather
        nid = csr[beg + lane];
        nw = dinv[nid];
    }
    unsigned u0 = ((const unsigned*)(h_bf + (size_t)v * DIM))[lane];
    float wself = dv * dv;                  // self-loop norm
    float2 bv = ((const float2*)bias)[lane];
    float2 acc;
    acc.x = bv.x + wself * bl(u0); acc.y = bv.y + wself * bh(u0);
    int n0 = min(num, 64);
    for (int i = 0; i < n0; ++i) {
        int s = __shfl(nid, i, 64);
        float w = dv * __shfl(nw, i, 64);
        unsigned u = ((const unsigned*)(h_bf + (size_t)s * DIM))[lane];
        acc.x += w * bl(u); acc.y += w * bh(u);
    }
    for (int i = 64; i < num; ++i) {        // cold fallback (deg>64 ~ impossible)
        int s = csr[beg + i];
        float w = dv * dinv[s];
        unsigned u = ((const unsigned*)(h_bf + (size_t)s * DIM))[lane];
        acc.x += w * bl(u); acc.y += w * bh(u);
    }
    nodes_h[(size_t)v * (DIM / 2) + lane] =
        (unsigned)f2bf(acc.x) | ((unsigned)f2bf(acc.y) << 16);
}

// ---------- K6: scores[b,s] = dot(nodes[items[b]], nodes[samples[b,s]]) ----------
// one block per item; 4 threads per sample (each owns 32 dims).
// Item row broadcast across the block via L1; sample rows are the 1M gathers.
__global__ __launch_bounds__(256) void k_score(const unsigned short* __restrict__ nodes_h,
                      const int* __restrict__ items, const int* __restrict__ samples,
                      float* __restrict__ out) {
    int b = blockIdx.x;
    int t = threadIdx.x;
    int q = t & 3;       // dim-chunk 0..3 (32 dims each)
    int sidx = t >> 2;   // sample 0..63
    int item = items[b];
    const uint4* irow = (const uint4*)(nodes_h + (size_t)item * DIM) + q * 4;
    uint4 a[4];
    #pragma unroll
    for (int c = 0; c < 4; ++c) a[c] = irow[c];    // L1-hot after first wave

    int j = samples[b * SAMP + sidx];
    const uint4* srow = (const uint4*)(nodes_h + (size_t)j * DIM) + q * 4;
    uint4 s4[4];
    #pragma unroll
    for (int c = 0; c < 4; ++c) s4[c] = srow[c];   // 4 independent 16B loads in flight

    float p = 0.f;
    #pragma unroll
    for (int c = 0; c < 4; ++c) {
        uint4 av = a[c], sv = s4[c];
        p += bl(av.x) * bl(sv.x) + bh(av.x) * bh(sv.x);
        p += bl(av.y) * bl(sv.y) + bh(av.y) * bh(sv.y);
        p += bl(av.z) * bl(sv.z) + bh(av.z) * bh(sv.z);
        p += bl(av.w) * bl(sv.w) + bh(av.w) * bh(sv.w);
    }
    p += __shfl_xor(p, 1, 64);
    p += __shfl_xor(p, 2, 64);
    if (q == 0) out[b * SAMP + sidx] = p;
}

extern "C" void kernel_launch(void* const* d_in, const int* in_sizes, int n_in,
                              void* d_out, int out_size, void* d_ws, size_t ws_size,
                              hipStream_t stream) {
    const int*   items   = (const int*)d_in[0];
    const int*   samples = (const int*)d_in[1];
    const int*   edges   = (const int*)d_in[2];
    const float* emb     = (const float*)d_in[3];
    const float* W       = (const float*)d_in[4];
    const float* bias    = (const float*)d_in[5];
    float* out = (float*)d_out;

    char* ws = (char*)d_ws;
    int*   cnt    = (int*)(ws + 0);                        // V ints (400 KB)
    int*   cursor = (int*)(ws + (512 << 10));              // V ints
    float* dinv   = (float*)(ws + (1 << 20));              // V floats
    int*   offs   = (int*)(ws + 3 * (512 << 10));          // V ints
    int*   bsum   = (int*)(ws + (2 << 20));                // 98 ints
    int*   boff   = (int*)(ws + (2 << 20) + (4 << 10));    // 98 ints
    int*   csr    = (int*)(ws + (4 << 20));                // E ints (2.56 MB)
    unsigned short* h_bf    = (unsigned short*)(ws + (8 << 20));   // V*DIM bf16 (25.6 MB)
    unsigned*       nodes_h = (unsigned*)(ws + (34 << 20));        // V*DIM bf16 (25.6 MB)

    const int* esrc = edges;
    const int* edst = edges + NEDGE;

    hipMemsetAsync(ws, 0, (1 << 20), stream);   // zero cnt + cursor

    int nb = (V_NODES + 1023) / 1024;   // 98
    // edge CSR (by dst)
    k_count<<<(NEDGE + 255) / 256, 256, 0, stream>>>(edst, cnt, NEDGE);
    k_bsum <<<nb, 256, 0, stream>>>(cnt, bsum, V_NODES);
    k_bscan<<<1, 64, 0, stream>>>(bsum, boff, nb);
    k_offs <<<nb, 256, 0, stream>>>(cnt, boff, offs, dinv, V_NODES);
    k_fill <<<(NEDGE + 255) / 256, 256, 0, stream>>>(esrc, edst, offs, cursor, csr, NEDGE);
    // GCN: GEMM first (reference order), then aggregate
    k_hgemm<<<V_NODES / 32, 256, 0, stream>>>(emb, h_bf, W, V_NODES);
    k_agg  <<<(V_NODES + 3) / 4, 256, 0, stream>>>(h_bf, offs, cnt, csr, dinv, bias, nodes_h, V_NODES);
    // scoring
    k_score<<<BATCH, 256, 0, stream>>>((const unsigned short*)nodes_h, items, samples, out);
}

// Round 8
// 204.282 us; speedup vs baseline: 1.8023x; 1.0992x over previous
//
#include <hip/hip_runtime.h>
#include <hip/hip_bf16.h>

#define V_NODES 100000
#define DIM 128
#define BATCH 16384
#define SAMP 64
#define NEDGE 640000
#define NSAMP (BATCH * SAMP)

// bf16 helpers: raw-bit unpack (exact) and RNE pack
__device__ __forceinline__ float bl(unsigned u) { return __uint_as_float(u << 16); }
__device__ __forceinline__ float bh(unsigned u) { return __uint_as_float(u & 0xffff0000u); }
__device__ __forceinline__ unsigned short f2bf(float x) {
    unsigned u = __float_as_uint(x);
    return (unsigned short)((u + 0x7fffu + ((u >> 16) & 1u)) >> 16);
}

typedef __attribute__((ext_vector_type(8))) short bf16x8;
typedef __attribute__((ext_vector_type(4))) float f32x4;

// ---------- K1: histogram of edge destinations (in-degree) ----------
__global__ void k_count(const int* __restrict__ key, int* __restrict__ cnt, int E) {
    int e = blockIdx.x * blockDim.x + threadIdx.x;
    if (e < E) atomicAdd(&cnt[key[e]], 1);
}

// ---------- K2a: per-1024-chunk sums ----------
__global__ void k_bsum(const int* __restrict__ cnt, int* __restrict__ bsum, int V) {
    __shared__ int red[4];
    int b = blockIdx.x, t = threadIdx.x;
    int s = 0;
    int base = b * 1024;
    for (int i = 0; i < 4; ++i) {
        int idx = base + i * 256 + t;
        if (idx < V) s += cnt[idx];
    }
    for (int m = 32; m >= 1; m >>= 1) s += __shfl_xor(s, m, 64);
    int lane = t & 63, wid = t >> 6;
    if (lane == 0) red[wid] = s;
    __syncthreads();
    if (t == 0) bsum[b] = red[0] + red[1] + red[2] + red[3];
}

// ---------- K2b: single-WAVE shuffle scan of chunk sums (was serial 1-thread) ----------
__global__ void k_bscan(const int* __restrict__ bsum, int* __restrict__ boff, int nb) {
    int l = threadIdx.x;            // 64 threads, 2 elements per lane
    int i0 = 2 * l, i1 = 2 * l + 1;
    int v0 = (i0 < nb) ? bsum[i0] : 0;
    int v1 = (i1 < nb) ? bsum[i1] : 0;
    int s = v0 + v1;
    int x = s;
    for (int off = 1; off < 64; off <<= 1) {
        int n = __shfl_up(x, off, 64);
        if (l >= off) x += n;
    }
    int excl = x - s;
    if (i0 < nb) boff[i0] = excl;
    if (i1 < nb) boff[i1] = excl + v0;
}

// ---------- K2c: exclusive CSR offsets + dinv = 1/sqrt(deg+1) ----------
__global__ void k_offs(const int* __restrict__ cnt, const int* __restrict__ boff,
                       int* __restrict__ offs, float* __restrict__ dinv, int V) {
    __shared__ int wsum[4];
    int b = blockIdx.x, t = threadIdx.x;
    int lane = t & 63, wid = t >> 6;
    int base = b * 1024 + t * 4;
    int c[4];
    for (int j = 0; j < 4; ++j) {
        int idx = base + j;
        c[j] = (idx < V) ? cnt[idx] : 0;
    }
    int tot = c[0] + c[1] + c[2] + c[3];
    int x = tot;
    for (int off = 1; off < 64; off <<= 1) {
        int n = __shfl_up(x, off, 64);
        if (lane >= off) x += n;
    }
    int lex = x - tot;
    if (lane == 63) wsum[wid] = x;
    __syncthreads();
    int wpre = 0;
    for (int w = 0; w < wid; ++w) wpre += wsum[w];
    int o = boff[b] + wpre + lex;
    int pre = 0;
    for (int j = 0; j < 4; ++j) {
        int idx = base + j;
        if (idx < V) {
            offs[idx] = o + pre;
            dinv[idx] = 1.0f / sqrtf((float)(c[j] + 1));
        }
        pre += c[j];
    }
}

// ---------- K3: fill edge CSR (int atomic cursors) ----------
__global__ void k_fill(const int* __restrict__ src, const int* __restrict__ dst,
                       const int* __restrict__ offs, int* __restrict__ cursor,
                       int* __restrict__ csr, int E) {
    int e = blockIdx.x * blockDim.x + threadIdx.x;
    if (e < E) {
        int d = dst[e];
        int pos = atomicAdd(&cursor[d], 1);
        csr[offs[d] + pos] = src[e];
    }
}

// ---------- K4: MFMA GEMM  h_bf = bf16(bf16(emb) @ bf16(W)) ----------
// block = 256 thr = 4 waves; 64 rows x 128 cols out per block.
// Wave w computes rows [w*16, w*16+16) x all 128 cols: 8 n-tiles of
// mfma_f32_16x16x32_bf16, K-loop of 4. Wt staged transposed with +8 pad
// (row stride 272 B -> bank stride 4 -> 2-way conflict = free).
#define WTP 136
__global__ __launch_bounds__(256) void k_hgemm(const float* __restrict__ emb,
                      unsigned short* __restrict__ h_bf,
                      const float* __restrict__ W, int V) {
    __shared__ unsigned short At[64][WTP];    // A tile bf16 (also reused for D out)
    __shared__ unsigned short Wt[128][WTP];   // W^T bf16
    int t = threadIdx.x;
    int rowbase = blockIdx.x * 64;
    // stage Wt[n][k] = bf16(W[k][n]) — coalesced float4 reads, scattered 2B LDS writes
    for (int i = t; i < 128 * 32; i += 256) {
        int k  = i >> 5;
        int n4 = (i & 31) << 2;
        float4 w4 = *(const float4*)(W + k * 128 + n4);
        Wt[n4 + 0][k] = f2bf(w4.x);
        Wt[n4 + 1][k] = f2bf(w4.y);
        Wt[n4 + 2][k] = f2bf(w4.z);
        Wt[n4 + 3][k] = f2bf(w4.w);
    }
    // stage A rows as bf16 (zero-pad rows >= V)
    for (int i = t; i < 64 * 32; i += 256) {
        int r  = i >> 5;
        int c4 = (i & 31) << 2;
        int gr = rowbase + r;
        float4 a4 = (gr < V) ? *(const float4*)(emb + (size_t)gr * 128 + c4)
                             : make_float4(0.f, 0.f, 0.f, 0.f);
        ushort4 p;
        p.x = f2bf(a4.x); p.y = f2bf(a4.y); p.z = f2bf(a4.z); p.w = f2bf(a4.w);
        *(ushort4*)&At[r][c4] = p;
    }
    __syncthreads();
    int wid = t >> 6, lane = t & 63;
    int r16  = lane & 15;        // row within 16-tile (A) / col within tile (B,D)
    int kgrp = lane >> 4;        // k-group 0..3 (8 k each)
    f32x4 acc[8] = {};
    #pragma unroll
    for (int ks = 0; ks < 4; ++ks) {
        bf16x8 a = *(const bf16x8*)&At[wid * 16 + r16][ks * 32 + kgrp * 8];
        #pragma unroll
        for (int n = 0; n < 8; ++n) {
            bf16x8 b = *(const bf16x8*)&Wt[n * 16 + r16][ks * 32 + kgrp * 8];
            acc[n] = __builtin_amdgcn_mfma_f32_16x16x32_bf16(a, b, acc[n], 0, 0, 0);
        }
    }
    __syncthreads();
    // D -> LDS (bf16), then coalesced global store
    #pragma unroll
    for (int n = 0; n < 8; ++n) {
        #pragma unroll
        for (int r = 0; r < 4; ++r) {
            At[wid * 16 + kgrp * 4 + r][n * 16 + r16] = f2bf(acc[n][r]);
        }
    }
    __syncthreads();
    for (int i = t; i < 64 * 16; i += 256) {
        int r  = i >> 4;
        int c8 = (i & 15) << 3;
        int gr = rowbase + r;
        if (gr < V) *(uint4*)(h_bf + (size_t)gr * 128 + c8) = *(const uint4*)&At[r][c8];
    }
}

// ---------- K5: aggregate h (post-GEMM), + bias, write bf16 nodes ----------
__global__ __launch_bounds__(256) void k_agg(const unsigned short* __restrict__ h_bf,
                     const int* __restrict__ offs, const int* __restrict__ cnt,
                     const int* __restrict__ csr, const float* __restrict__ dinv,
                     const float* __restrict__ bias,
                     unsigned* __restrict__ nodes_h, int V) {
    int wid = threadIdx.x >> 6;
    int lane = threadIdx.x & 63;
    int v = blockIdx.x * 4 + wid;
    if (v >= V) return;
    float dv = dinv[v];
    int beg = offs[v], num = cnt[v];
    int nid = 0; float nw = 0.0f;
    if (lane < num) {
        nid = csr[beg + lane];
        nw = dinv[nid];
    }
    unsigned u0 = ((const unsigned*)(h_bf + (size_t)v * DIM))[lane];
    float wself = dv * dv;
    float2 bv = ((const float2*)bias)[lane];
    float2 acc;
    acc.x = bv.x + wself * bl(u0); acc.y = bv.y + wself * bh(u0);
    int n0 = min(num, 64);
    for (int i = 0; i < n0; ++i) {
        int s = __shfl(nid, i, 64);
        float w = dv * __shfl(nw, i, 64);
        unsigned u = ((const unsigned*)(h_bf + (size_t)s * DIM))[lane];
        acc.x += w * bl(u); acc.y += w * bh(u);
    }
    for (int i = 64; i < num; ++i) {
        int s = csr[beg + i];
        float w = dv * dinv[s];
        unsigned u = ((const unsigned*)(h_bf + (size_t)s * DIM))[lane];
        acc.x += w * bl(u); acc.y += w * bh(u);
    }
    nodes_h[(size_t)v * (DIM / 2) + lane] =
        (unsigned)f2bf(acc.x) | ((unsigned)f2bf(acc.y) << 16);
}

// ---------- K6: scores[b,s] = dot(nodes[items[b]], nodes[samples[b,s]]) ----------
__global__ __launch_bounds__(256) void k_score(const unsigned short* __restrict__ nodes_h,
                      const int* __restrict__ items, const int* __restrict__ samples,
                      float* __restrict__ out) {
    int b = blockIdx.x;
    int t = threadIdx.x;
    int q = t & 3;
    int sidx = t >> 2;
    int item = items[b];
    const uint4* irow = (const uint4*)(nodes_h + (size_t)item * DIM) + q * 4;
    uint4 a[4];
    #pragma unroll
    for (int c = 0; c < 4; ++c) a[c] = irow[c];

    int j = samples[b * SAMP + sidx];
    const uint4* srow = (const uint4*)(nodes_h + (size_t)j * DIM) + q * 4;
    uint4 s4[4];
    #pragma unroll
    for (int c = 0; c < 4; ++c) s4[c] = srow[c];

    float p = 0.f;
    #pragma unroll
    for (int c = 0; c < 4; ++c) {
        uint4 av = a[c], sv = s4[c];
        p += bl(av.x) * bl(sv.x) + bh(av.x) * bh(sv.x);
        p += bl(av.y) * bl(sv.y) + bh(av.y) * bh(sv.y);
        p += bl(av.z) * bl(sv.z) + bh(av.z) * bh(sv.z);
        p += bl(av.w) * bl(sv.w) + bh(av.w) * bh(sv.w);
    }
    p += __shfl_xor(p, 1, 64);
    p += __shfl_xor(p, 2, 64);
    if (q == 0) out[b * SAMP + sidx] = p;
}

extern "C" void kernel_launch(void* const* d_in, const int* in_sizes, int n_in,
                              void* d_out, int out_size, void* d_ws, size_t ws_size,
                              hipStream_t stream) {
    const int*   items   = (const int*)d_in[0];
    const int*   samples = (const int*)d_in[1];
    const int*   edges   = (const int*)d_in[2];
    const float* emb     = (const float*)d_in[3];
    const float* W       = (const float*)d_in[4];
    const float* bias    = (const float*)d_in[5];
    float* out = (float*)d_out;

    char* ws = (char*)d_ws;
    int*   cnt    = (int*)(ws + 0);                        // V ints (400 KB)
    int*   cursor = (int*)(ws + (512 << 10));              // V ints
    float* dinv   = (float*)(ws + (1 << 20));              // V floats
    int*   offs   = (int*)(ws + 3 * (512 << 10));          // V ints
    int*   bsum   = (int*)(ws + (2 << 20));                // 98 ints
    int*   boff   = (int*)(ws + (2 << 20) + (4 << 10));    // 98 ints
    int*   csr    = (int*)(ws + (4 << 20));                // E ints (2.56 MB)
    unsigned short* h_bf    = (unsigned short*)(ws + (8 << 20));   // V*DIM bf16 (25.6 MB)
    unsigned*       nodes_h = (unsigned*)(ws + (34 << 20));        // V*DIM bf16 (25.6 MB)

    const int* esrc = edges;
    const int* edst = edges + NEDGE;

    hipMemsetAsync(ws, 0, (1 << 20), stream);   // zero cnt + cursor

    int nb = (V_NODES + 1023) / 1024;   // 98
    // edge CSR (by dst)
    k_count<<<(NEDGE + 255) / 256, 256, 0, stream>>>(edst, cnt, NEDGE);
    k_bsum <<<nb, 256, 0, stream>>>(cnt, bsum, V_NODES);
    k_bscan<<<1, 64, 0, stream>>>(bsum, boff, nb);
    k_offs <<<nb, 256, 0, stream>>>(cnt, boff, offs, dinv, V_NODES);
    k_fill <<<(NEDGE + 255) / 256, 256, 0, stream>>>(esrc, edst, offs, cursor, csr, NEDGE);
    // GCN: MFMA GEMM first (reference order), then aggregate
    k_hgemm<<<(V_NODES + 63) / 64, 256, 0, stream>>>(emb, h_bf, W, V_NODES);
    k_agg  <<<(V_NODES + 3) / 4, 256, 0, stream>>>(h_bf, offs, cnt, csr, dinv, bias, nodes_h, V_NODES);
    // scoring
    k_score<<<BATCH, 256, 0, stream>>>((const unsigned short*)nodes_h, items, samples, out);
}